// Round 9
// baseline (1240.572 us; speedup 1.0000x reference)
//
#include <hip/hip_runtime.h>
#include <math.h>

#define NN 50000
#define DD 128
#define ET_N 640000
#define EH_N 320000
#define NL 3

static inline int cdiv(int a, int b){ return (a+b-1)/b; }

typedef __attribute__((ext_vector_type(8))) short short8;
typedef __attribute__((ext_vector_type(4))) float f32x4;

// ---------------- compiled-in device scratch (no d_ws dependency) ----------------
__device__ float   g_h [(size_t)NN*DD];
__device__ unsigned short g_hb[(size_t)NN*DD];        // bf16 copy of h (GEMM A input)
__device__ unsigned short g_Wb[(size_t)NL*8*DD*DD];   // bf16, TRANSPOSED [n][k]; l*8 + {tQ,tK,tV,tS,hQ,hK,hV,hS}
__device__ float   g_Q [2][(size_t)NN*DD];
__device__ float   g_S [2][(size_t)NN*DD];
__device__ ushort2 g_KV[2][(size_t)NN*DD];   // .x = K bf16 bits, .y = V bf16 bits
__device__ float   g_to[(size_t)NN*DD];      // temporal conv output
__device__ float   g_ho[(size_t)NN*DD];      // host conv output
__device__ int     g_cnt[2][NN];
__device__ int     g_cur[2][NN];
__device__ int     g_rs [2][NN+1];
__device__ int     g_srcc[2][ET_N];          // CSR-ordered src (conv1 uses first EH_N)
__device__ float   g_ta[ET_N];               // CSR-ordered temporal attr (scalar)
__device__ float4  g_ha[EH_N];               // CSR-ordered host attr (3 used)

__device__ inline unsigned short f2bf(float f){
  unsigned u = __float_as_uint(f);
  unsigned r = (u + 0x7fffu + ((u>>16)&1u)) >> 16;   // RNE
  return (unsigned short)r;
}
__device__ inline float bf2f(unsigned short s){
  return __uint_as_float(((unsigned)s)<<16);
}
__device__ inline float bf_lo(unsigned u){ return __uint_as_float(u<<16); }
__device__ inline float bf_hi(unsigned u){ return __uint_as_float(u & 0xffff0000u); }

// ---------------- tiny helpers ----------------
__global__ void k_copy_h(const float* __restrict__ x){
  int i = blockIdx.x*256 + threadIdx.x;           // float4 index
  if (i < NN*DD/4){
    float4 v = reinterpret_cast<const float4*>(x)[i];
    reinterpret_cast<float4*>(g_h)[i] = v;
    ushort4 b; b.x=f2bf(v.x); b.y=f2bf(v.y); b.z=f2bf(v.z); b.w=f2bf(v.w);
    reinterpret_cast<ushort4*>(g_hb)[i] = b;
  }
}

__global__ void k_zero_cnt(){
  int i = blockIdx.x*256 + threadIdx.x;
  if (i < NN) g_cnt[blockIdx.y][i] = 0;
}

// convert + transpose conv weights to bf16 [n][k]
struct WPtrs { const float* W[24]; };
__global__ __launch_bounds__(256) void k_cvtw(WPtrs wp){
  int mat = blockIdx.y;
  const float* W = wp.W[mat];
  int e = blockIdx.x*256 + threadIdx.x;
  int n = e >> 7, k = e & 127;
  g_Wb[(size_t)mat*DD*DD + e] = f2bf(W[k*DD+n]);
}

// ---------- CSR build (by destination) ----------
__global__ void k_hist(const int* __restrict__ dstT, const int* __restrict__ dstH){
  int which = blockIdx.y;
  int E = which ? EH_N : ET_N;
  const int* dst = which ? dstH : dstT;
  int e = blockIdx.x*256+threadIdx.x;
  if (e<E) atomicAdd(&g_cnt[which][dst[e]], 1);
}

__global__ __launch_bounds__(1024) void k_scan(){
  int which = blockIdx.y;
  int* row_start = g_rs[which];
  const int* cnt = g_cnt[which];
  int* cur = g_cur[which];
  __shared__ int buf[1024];
  int tid = threadIdx.x;
  const int n = NN;
  int chunk = (n + 1023) >> 10;
  int start = tid*chunk; if (start>n) start=n;
  int end = start+chunk; if (end>n) end=n;
  int lsum=0;
  for (int i=start;i<end;++i) lsum += cnt[i];
  buf[tid]=lsum;
  __syncthreads();
  for (int off=1; off<1024; off<<=1){
    int t = (tid>=off)? buf[tid-off]:0;
    __syncthreads();
    buf[tid] += t;
    __syncthreads();
  }
  int run = buf[tid]-lsum;
  for (int i=start;i<end;++i){ row_start[i]=run; cur[i]=run; run += cnt[i]; }
  if (tid==1023) row_start[n]=run;
}

// scatter: CSR-ordered src + raw edge attrs
__global__ void k_scatter(const int* __restrict__ eit, const int* __restrict__ eih,
                          const float* __restrict__ attrT, const float* __restrict__ attrH){
  int which = blockIdx.y;
  int e = blockIdx.x*256+threadIdx.x;
  if (which==0){
    if (e>=ET_N) return;
    int src = eit[e], dst = eit[ET_N+e];
    int p = atomicAdd(&g_cur[0][dst],1);
    g_srcc[0][p]=src;
    g_ta[p]=attrT[e];
  } else {
    if (e>=EH_N) return;
    int src = eih[e], dst = eih[EH_N+e];
    int p = atomicAdd(&g_cur[1][dst],1);
    g_srcc[1][p]=src;
    g_ha[p]=make_float4(attrH[e*3+0],attrH[e*3+1],attrH[e*3+2],0.f);
  }
}

// ---------- bf16 MFMA GEMM: one block computes Q,K,V,S for its 64-row tile ----------
struct BiasP { const float* b[8]; };

__global__ __launch_bounds__(256) void k_gemm_mfma(int l, BiasP bp){
  __shared__ unsigned short lA[64*DD];    // 16 KB
  __shared__ unsigned short lB[DD*DD];    // 32 KB
  int conv = blockIdx.y;
  int setbase = l*8 + conv*4;             // +0 Q, +1 K, +2 V, +3 S
  int tid = threadIdx.x;
  int m0 = blockIdx.x*64;

#pragma unroll
  for (int p=0;p<4;++p){
    int c = tid + p*256;
    int row = c >> 4, col16 = c & 15;
    int grow = m0 + row;
    uint4 v = make_uint4(0,0,0,0);
    if (grow < NN) v = *reinterpret_cast<const uint4*>(&g_hb[(size_t)grow*DD + col16*8]);
    int off = (row*256 + col16*16) ^ ((row&7)<<4);
    *reinterpret_cast<uint4*>((char*)lA + off) = v;
  }

  int wave = tid >> 6, lane = tid & 63;
  int lrow = lane & 15, kg = lane >> 4;
  int n0w = wave*32;

  auto stageB = [&](const unsigned short* Wm){
#pragma unroll
    for (int p=0;p<8;++p){
      int c = tid + p*256;
      int row = c >> 4, col16 = c & 15;
      uint4 v = *reinterpret_cast<const uint4*>(&Wm[(size_t)row*DD + col16*8]);
      int off = (row*256 + col16*16) ^ ((row&7)<<4);
      *reinterpret_cast<uint4*>((char*)lB + off) = v;
    }
  };

  stageB(&g_Wb[(size_t)(setbase+0)*DD*DD]);   // Q weights
  __syncthreads();

  short8 a[4][4];
#pragma unroll
  for (int kk=0;kk<4;++kk){
    int kbyte = kk*64 + kg*16;
#pragma unroll
    for (int mi=0;mi<4;++mi){
      int row = mi*16 + lrow;
      int off = (row*256 + kbyte) ^ ((row&7)<<4);
      a[kk][mi] = *reinterpret_cast<const short8*>((char*)lA + off);
    }
  }

  auto computeC = [&](f32x4 (&acc)[4][2]){
#pragma unroll
    for (int mi=0;mi<4;++mi)
#pragma unroll
      for (int ni=0;ni<2;++ni) acc[mi][ni] = (f32x4){0.f,0.f,0.f,0.f};
#pragma unroll
    for (int kk=0;kk<4;++kk){
      int kbyte = kk*64 + kg*16;
      short8 b[2];
#pragma unroll
      for (int ni=0;ni<2;++ni){
        int n = n0w + ni*16 + lrow;
        int off = (n*256 + kbyte) ^ ((n&7)<<4);
        b[ni] = *reinterpret_cast<const short8*>((char*)lB + off);
      }
#pragma unroll
      for (int mi=0;mi<4;++mi)
#pragma unroll
        for (int ni=0;ni<2;++ni)
          acc[mi][ni] = __builtin_amdgcn_mfma_f32_16x16x32_bf16(a[kk][mi], b[ni], acc[mi][ni], 0,0,0);
    }
  };

  f32x4 acc[4][2], accK[4][2];

  // ---- Q ----
  computeC(acc);
  {
    const float* bias = bp.b[conv*4+0];
    float* op = g_Q[conv];
#pragma unroll
    for (int ni=0;ni<2;++ni){
      int col = n0w + ni*16 + lrow;
      float bs = bias[col];
#pragma unroll
      for (int mi=0;mi<4;++mi)
#pragma unroll
        for (int r=0;r<4;++r){
          int row = m0 + mi*16 + kg*4 + r;
          if (row < NN) op[(size_t)row*DD + col] = acc[mi][ni][r] + bs;
        }
    }
  }
  __syncthreads();
  // ---- K (keep in regs) ----
  stageB(&g_Wb[(size_t)(setbase+1)*DD*DD]);
  __syncthreads();
  computeC(accK);
  __syncthreads();
  // ---- V, then pack KV ----
  stageB(&g_Wb[(size_t)(setbase+2)*DD*DD]);
  __syncthreads();
  computeC(acc);
  {
    const float* bK = bp.b[conv*4+1];
    const float* bV = bp.b[conv*4+2];
#pragma unroll
    for (int ni=0;ni<2;++ni){
      int col = n0w + ni*16 + lrow;
      float bk = bK[col], bv = bV[col];
#pragma unroll
      for (int mi=0;mi<4;++mi)
#pragma unroll
        for (int r=0;r<4;++r){
          int row = m0 + mi*16 + kg*4 + r;
          if (row < NN){
            ushort2 kv;
            kv.x = f2bf(accK[mi][ni][r] + bk);
            kv.y = f2bf(acc [mi][ni][r] + bv);
            g_KV[conv][(size_t)row*DD + col] = kv;
          }
        }
    }
  }
  __syncthreads();
  // ---- S ----
  stageB(&g_Wb[(size_t)(setbase+3)*DD*DD]);
  __syncthreads();
  computeC(acc);
  {
    const float* bias = bp.b[conv*4+3];
    float* op = g_S[conv];
#pragma unroll
    for (int ni=0;ni<2;++ni){
      int col = n0w + ni*16 + lrow;
      float bs = bias[col];
#pragma unroll
      for (int mi=0;mi<4;++mi)
#pragma unroll
        for (int r=0;r<4;++r){
          int row = m0 + mi*16 + kg*4 + r;
          if (row < NN) op[(size_t)row*DD + col] = acc[mi][ni][r] + bs;
        }
    }
  }
}

// ---------- wave helpers ----------
__device__ inline float waveRed(float v){
  v += __shfl_xor(v,32); v += __shfl_xor(v,16); v += __shfl_xor(v,8);
  v += __shfl_xor(v,4);  v += __shfl_xor(v,2);  v += __shfl_xor(v,1);
  return v;
}

// ---------- per-dst-node attention aggregation ----------
// grid (cdiv(NN,4), 2); block 256 = 4 independent waves, one node per wave.
// Wave layout: subgroup g = lane>>4 handles edges beg+it*4+g; sublane t = lane&15
// holds channels 8t..8t+7 (head = t>>2, 4 sublanes per head).
// No running max (logits bounded ~O(5): exp f32-safe; matches reference math).
__global__ __launch_bounds__(256) void k_agg(
    const float* __restrict__ WeT, const float* __restrict__ WeH,
    const float* __restrict__ Wt,  const float* __restrict__ bt4,
    const float* __restrict__ Wh,  const float* __restrict__ bh4){
  int conv = blockIdx.y;
  int wave = threadIdx.x >> 6;
  int lane = threadIdx.x & 63;
  int i = blockIdx.x*4 + wave;
  if (i >= NN) return;
  int g = lane >> 4;
  int t = lane & 15;
  int ch0 = t*8;

  // q: this lane's 8 channels
  const float* Qi = &g_Q[conv][(size_t)i*DD + ch0];
  float q[8];
  {
    float4 qA = *reinterpret_cast<const float4*>(Qi);
    float4 qB = *reinterpret_cast<const float4*>(Qi+4);
    q[0]=qA.x;q[1]=qA.y;q[2]=qA.z;q[3]=qA.w;q[4]=qB.x;q[5]=qB.y;q[6]=qB.z;q[7]=qB.w;
  }

  // fold edge-encoder @ lin_edge: per-channel coefficients (cB = bias fold; cA* = attr coeffs)
  float cB[8], cA0[8], cA1[8], cA2[8];
#pragma unroll
  for (int r=0;r<8;++r){ cB[r]=0.f; cA0[r]=0.f; cA1[r]=0.f; cA2[r]=0.f; }
  if (conv==0){
#pragma unroll
    for (int j=0;j<4;++j){
      float4 wA = *reinterpret_cast<const float4*>(&WeT[j*DD+ch0]);
      float4 wB = *reinterpret_cast<const float4*>(&WeT[j*DD+ch0+4]);
      float w[8]={wA.x,wA.y,wA.z,wA.w,wB.x,wB.y,wB.z,wB.w};
      float bj=bt4[j], aj=Wt[j];
#pragma unroll
      for (int r=0;r<8;++r){ cB[r] += bj*w[r]; cA0[r] += aj*w[r]; }
    }
  } else {
#pragma unroll
    for (int j=0;j<4;++j){
      float4 wA = *reinterpret_cast<const float4*>(&WeH[j*DD+ch0]);
      float4 wB = *reinterpret_cast<const float4*>(&WeH[j*DD+ch0+4]);
      float w[8]={wA.x,wA.y,wA.z,wA.w,wB.x,wB.y,wB.z,wB.w};
      float a0=Wh[j], a1=Wh[4+j], a2=Wh[8+j], bj=bh4[j];
#pragma unroll
      for (int r=0;r<8;++r){ cA0[r]+=a0*w[r]; cA1[r]+=a1*w[r]; cA2[r]+=a2*w[r]; cB[r]+=bj*w[r]; }
    }
  }

  // per-head q.c scalars (reduce over head's 4 sublanes)
  float qeB=0.f, qe0=0.f, qe1=0.f, qe2=0.f;
#pragma unroll
  for (int r=0;r<8;++r){ qeB += q[r]*cB[r]; qe0 += q[r]*cA0[r]; }
  qeB += __shfl_xor(qeB,1); qeB += __shfl_xor(qeB,2);
  qe0 += __shfl_xor(qe0,1); qe0 += __shfl_xor(qe0,2);
  if (conv==1){
#pragma unroll
    for (int r=0;r<8;++r){ qe1 += q[r]*cA1[r]; qe2 += q[r]*cA2[r]; }
    qe1 += __shfl_xor(qe1,1); qe1 += __shfl_xor(qe1,2);
    qe2 += __shfl_xor(qe2,1); qe2 += __shfl_xor(qe2,2);
  }

  const int* srcc = g_srcc[conv];
  const char* KVbase = (const char*)g_KV[conv];
  int beg=g_rs[conv][i], end=g_rs[conv][i+1];
  int cnt = end-beg;

  const float inv32 = 0.17677669529663687f;   // 1/sqrt(32)
  float den=0.f, x0=0.f, x1=0.f, x2=0.f;
  float ac[8];
#pragma unroll
  for (int r=0;r<8;++r) ac[r]=0.f;

  if (cnt>0){
    int nit = (cnt+3)>>2;
    int idx = beg + g;
    bool val = idx < end;
    int sidx = val ? idx : beg;
    int s = srcc[sidx];
    float4 at = make_float4(0.f,0.f,0.f,0.f);
    if (conv==0) at.x = g_ta[sidx]; else at = g_ha[sidx];
    const uint4* rp = reinterpret_cast<const uint4*>(KVbase + (size_t)s*512 + t*32);
    uint4 u0 = rp[0], u1 = rp[1];

    for (int it=0; it<nit; ++it){
      uint4 cu0=u0, cu1=u1; float4 ca=at; bool cval=val;
      if (it+1<nit){
        int nidx = beg + (it+1)*4 + g;
        val = nidx < end;
        int ns = srcc[val?nidx:beg];
        if (conv==0) at.x = g_ta[val?nidx:beg]; else at = g_ha[val?nidx:beg];
        rp = reinterpret_cast<const uint4*>(KVbase + (size_t)ns*512 + t*32);
        u0 = rp[0]; u1 = rp[1];
      }
      float k[8], v[8];
      k[0]=bf_lo(cu0.x); v[0]=bf_hi(cu0.x);
      k[1]=bf_lo(cu0.y); v[1]=bf_hi(cu0.y);
      k[2]=bf_lo(cu0.z); v[2]=bf_hi(cu0.z);
      k[3]=bf_lo(cu0.w); v[3]=bf_hi(cu0.w);
      k[4]=bf_lo(cu1.x); v[4]=bf_hi(cu1.x);
      k[5]=bf_lo(cu1.y); v[5]=bf_hi(cu1.y);
      k[6]=bf_lo(cu1.z); v[6]=bf_hi(cu1.z);
      k[7]=bf_lo(cu1.w); v[7]=bf_hi(cu1.w);
      float p = 0.f;
#pragma unroll
      for (int r=0;r<8;++r) p += q[r]*k[r];
      p += __shfl_xor(p,1); p += __shfl_xor(p,2);   // head dot (32 ch)
      float lg = (conv==0) ? (p + qeB + ca.x*qe0)*inv32
                           : (p + ca.x*qe0 + ca.y*qe1 + ca.z*qe2 + qeB)*inv32;
      float e = cval ? __expf(lg) : 0.f;
      den += e;
#pragma unroll
      for (int r=0;r<8;++r) ac[r] += e*v[r];
      x0 += e*ca.x;
      if (conv==1){ x1 += e*ca.y; x2 += e*ca.z; }
    }
    // combine the 4 subgroup partials (per-head: lanes with same t share head)
    den += __shfl_xor(den,16); den += __shfl_xor(den,32);
    x0  += __shfl_xor(x0,16);  x0  += __shfl_xor(x0,32);
    if (conv==1){
      x1 += __shfl_xor(x1,16); x1 += __shfl_xor(x1,32);
      x2 += __shfl_xor(x2,16); x2 += __shfl_xor(x2,32);
    }
#pragma unroll
    for (int r=0;r<8;++r){ ac[r] += __shfl_xor(ac[r],16); ac[r] += __shfl_xor(ac[r],32); }
  }

  if (g==0){
    float r8[8];
    if (cnt==0){
#pragma unroll
      for (int r=0;r<8;++r) r8[r]=0.f;
    } else {
      float id = 1.f/den;
      if (conv==0){
        float xm = x0*id;
#pragma unroll
        for (int r=0;r<8;++r) r8[r] = ac[r]*id + cB[r] + cA0[r]*xm;
      } else {
        float xm0=x0*id, xm1=x1*id, xm2=x2*id;
#pragma unroll
        for (int r=0;r<8;++r) r8[r] = ac[r]*id + cA0[r]*xm0 + cA1[r]*xm1 + cA2[r]*xm2 + cB[r];
      }
    }
    const float* Si = &g_S[conv][(size_t)i*DD + ch0];
    float4 sA = *reinterpret_cast<const float4*>(Si);
    float4 sB = *reinterpret_cast<const float4*>(Si+4);
    float* o = (conv ? g_ho : g_to) + (size_t)i*DD + ch0;
    float4 oA, oB;
    oA.x=r8[0]+sA.x; oA.y=r8[1]+sA.y; oA.z=r8[2]+sA.z; oA.w=r8[3]+sA.w;
    oB.x=r8[4]+sB.x; oB.y=r8[5]+sB.y; oB.z=r8[6]+sB.z; oB.w=r8[7]+sB.w;
    *reinterpret_cast<float4*>(o)   = oA;
    *reinterpret_cast<float4*>(o+4) = oB;
  }
}

// g_h += silu(layernorm(g_to + g_ho)) ; one wave per node, 4 nodes per block
__global__ __launch_bounds__(256) void k_combine(const float* __restrict__ g, const float* __restrict__ bt){
  int lane = threadIdx.x & 63;
  int node = blockIdx.x*4 + (threadIdx.x>>6);
  if (node>=NN) return;
  size_t i0 = (size_t)node*DD + lane, i1 = i0+64;
  float v0 = g_to[i0] + g_ho[i0];
  float v1 = g_to[i1] + g_ho[i1];
  float s = waveRed(v0+v1);
  float mean = s*(1.f/128.f);
  float d0=v0-mean, d1=v1-mean;
  float q = waveRed(d0*d0+d1*d1);
  float inv = 1.f/sqrtf(q*(1.f/128.f)+1e-5f);
  float c0 = d0*inv*g[lane]+bt[lane];
  float c1 = d1*inv*g[lane+64]+bt[lane+64];
  float h0 = g_h[i0] + c0/(1.f+__expf(-c0));
  float h1 = g_h[i1] + c1/(1.f+__expf(-c1));
  g_h[i0] = h0; g_h[i1] = h1;
  g_hb[i0] = f2bf(h0); g_hb[i1] = f2bf(h1);
}

// in-place final layernorm on g_h
__global__ __launch_bounds__(256) void k_finalln(const float* __restrict__ g, const float* __restrict__ b){
  int lane = threadIdx.x & 63;
  int node = blockIdx.x*4 + (threadIdx.x>>6);
  if (node>=NN) return;
  size_t i0 = (size_t)node*DD + lane, i1 = i0+64;
  float v0 = g_h[i0], v1 = g_h[i1];
  float s = waveRed(v0+v1);
  float mean = s*(1.f/128.f);
  float d0=v0-mean, d1=v1-mean;
  float q = waveRed(d0*d0+d1*d1);
  float inv = 1.f/sqrtf(q*(1.f/128.f)+1e-5f);
  g_h[i0]=d0*inv*g[lane]+b[lane];
  g_h[i1]=d1*inv*g[lane+64]+b[lane+64];
}

// mlp head: out3 = LN(silu(g_h@W1+b1)) @ W2 + b2 ; 8 nodes per block
__global__ __launch_bounds__(128) void k_head(
      const float* __restrict__ W1, const float* __restrict__ b1,
      const float* __restrict__ g, const float* __restrict__ bt,
      const float* __restrict__ W2, const float* __restrict__ b2,
      float* __restrict__ out){
  int d = threadIdx.x;
  int wv = d >> 6;
  int i0 = blockIdx.x*8;
  const int n = NN;
  __shared__ float rows[8][DD];
  __shared__ float comb[2];
#pragma unroll
  for (int t=0;t<8;++t){
    int node = i0+t;
    rows[t][d] = (node<n)? g_h[(size_t)node*DD+d] : 0.f;
  }
  __syncthreads();
  float z[8];
  float b1d = b1[d];
#pragma unroll
  for (int t=0;t<8;++t) z[t]=b1d;
  for (int k=0;k<DD;++k){
    float w = W1[k*DD+d];
#pragma unroll
    for (int t=0;t<8;++t) z[t] += rows[t][k]*w;
  }
#pragma unroll
  for (int t=0;t<8;++t){ float v=z[t]; z[t] = v/(1.f+expf(-v)); }
  float gd=g[d], btd=bt[d];
  float w2a=W2[d*3+0], w2b=W2[d*3+1], w2c=W2[d*3+2];
  float b2a=b2[0], b2b=b2[1], b2c=b2[2];
  for (int t=0;t<8;++t){
    int node=i0+t;
    float zz=z[t];
    float s = waveRed(zz);
    if ((d&63)==0) comb[wv]=s;
    __syncthreads();
    float mean=(comb[0]+comb[1])*(1.f/128.f);
    __syncthreads();
    float dv=zz-mean;
    float q2 = waveRed(dv*dv);
    if ((d&63)==0) comb[wv]=q2;
    __syncthreads();
    float inv = 1.f/sqrtf((comb[0]+comb[1])*(1.f/128.f)+1e-5f);
    __syncthreads();
    float zn = dv*inv*gd+btd;
    float p0 = waveRed(zn*w2a);
    if ((d&63)==0) comb[wv]=p0;
    __syncthreads();
    float o0 = comb[0]+comb[1]+b2a;
    __syncthreads();
    float p1 = waveRed(zn*w2b);
    if ((d&63)==0) comb[wv]=p1;
    __syncthreads();
    float o1 = comb[0]+comb[1]+b2b;
    __syncthreads();
    float p2 = waveRed(zn*w2c);
    if ((d&63)==0) comb[wv]=p2;
    __syncthreads();
    float o2 = comb[0]+comb[1]+b2c;
    __syncthreads();
    if (d==0 && node<n){
      out[(size_t)node*3+0]=o0; out[(size_t)node*3+1]=o1; out[(size_t)node*3+2]=o2;
    }
  }
}

extern "C" void kernel_launch(void* const* d_in, const int* in_sizes, int n_in,
                              void* d_out, int out_size, void* d_ws, size_t ws_size,
                              hipStream_t stream){
  (void)in_sizes; (void)n_in; (void)out_size; (void)d_ws; (void)ws_size;
  const float* x    = (const float*)d_in[0];
  const int*   eit  = (const int*)d_in[1];
  const int*   eih  = (const int*)d_in[2];
  const float* eat  = (const float*)d_in[3];
  const float* eah  = (const float*)d_in[4];
  const float* W_te = (const float*)d_in[5];
  const float* b_te = (const float*)d_in[6];
  const float* W_he = (const float*)d_in[7];
  const float* b_he = (const float*)d_in[8];
  const float *Wq_t=(const float*)d_in[9],  *bq_t=(const float*)d_in[10];
  const float *Wk_t=(const float*)d_in[11], *bk_t=(const float*)d_in[12];
  const float *Wv_t=(const float*)d_in[13], *bv_t=(const float*)d_in[14];
  const float *We_t=(const float*)d_in[15];
  const float *Ws_t=(const float*)d_in[16], *bs_t=(const float*)d_in[17];
  const float *Wq_h=(const float*)d_in[18], *bq_h=(const float*)d_in[19];
  const float *Wk_h=(const float*)d_in[20], *bk_h=(const float*)d_in[21];
  const float *Wv_h=(const float*)d_in[22], *bv_h=(const float*)d_in[23];
  const float *We_h=(const float*)d_in[24];
  const float *Ws_h=(const float*)d_in[25], *bs_h=(const float*)d_in[26];
  const float *norm_g=(const float*)d_in[27], *norm_b=(const float*)d_in[28];
  const float *fg=(const float*)d_in[29], *fb=(const float*)d_in[30];
  const float *dW1=(const float*)d_in[31], *db1=(const float*)d_in[32];
  const float *dg=(const float*)d_in[33],  *dbt=(const float*)d_in[34];
  const float *dW2=(const float*)d_in[35], *db2=(const float*)d_in[36];
  const float *sW1=(const float*)d_in[37], *sb1=(const float*)d_in[38];
  const float *sg=(const float*)d_in[39],  *sbt=(const float*)d_in[40];
  const float *sW2=(const float*)d_in[41], *sb2=(const float*)d_in[42];
  float* outp = (float*)d_out;

  k_copy_h<<<cdiv(NN*DD/4,256),256,0,stream>>>(x);

  WPtrs wp;
  for (int l=0;l<NL;++l){
    wp.W[l*8+0]=Wq_t+(size_t)l*DD*DD; wp.W[l*8+1]=Wk_t+(size_t)l*DD*DD;
    wp.W[l*8+2]=Wv_t+(size_t)l*DD*DD; wp.W[l*8+3]=Ws_t+(size_t)l*DD*DD;
    wp.W[l*8+4]=Wq_h+(size_t)l*DD*DD; wp.W[l*8+5]=Wk_h+(size_t)l*DD*DD;
    wp.W[l*8+6]=Wv_h+(size_t)l*DD*DD; wp.W[l*8+7]=Ws_h+(size_t)l*DD*DD;
  }
  k_cvtw<<<dim3(64,24),256,0,stream>>>(wp);

  k_zero_cnt<<<dim3(cdiv(NN,256),2),256,0,stream>>>();
  k_hist<<<dim3(cdiv(ET_N,256),2),256,0,stream>>>(eit+ET_N, eih+EH_N);
  k_scan<<<dim3(1,2),1024,0,stream>>>();
  k_scatter<<<dim3(cdiv(ET_N,256),2),256,0,stream>>>(eit, eih, eat, eah);

  for (int l=0;l<NL;++l){
    BiasP bp;
    bp.b[0]=bq_t+(size_t)l*DD; bp.b[1]=bk_t+(size_t)l*DD;
    bp.b[2]=bv_t+(size_t)l*DD; bp.b[3]=bs_t+(size_t)l*DD;
    bp.b[4]=bq_h+(size_t)l*DD; bp.b[5]=bk_h+(size_t)l*DD;
    bp.b[6]=bv_h+(size_t)l*DD; bp.b[7]=bs_h+(size_t)l*DD;
    k_gemm_mfma<<<dim3(cdiv(NN,64),2),256,0,stream>>>(l, bp);
    k_agg<<<dim3(cdiv(NN,4),2),256,0,stream>>>(We_t+(size_t)l*4*DD, We_h+(size_t)l*4*DD,
                                               W_te, b_te, W_he, b_he);
    k_combine<<<cdiv(NN,4),256,0,stream>>>(norm_g+(size_t)l*DD, norm_b+(size_t)l*DD);
  }
  k_finalln<<<cdiv(NN,4),256,0,stream>>>(fg, fb);
  k_head<<<cdiv(NN,8),128,0,stream>>>(dW1, db1, dg, dbt, dW2, db2, outp);
  k_head<<<cdiv(NN,8),128,0,stream>>>(sW1, sb1, sg, sbt, sW2, sb2, outp+(size_t)NN*3);
}

// Round 11
// 1177.114 us; speedup vs baseline: 1.0539x; 1.0539x over previous
//
#include <hip/hip_runtime.h>
#include <math.h>

#define NN 50000
#define DD 128
#define ET_N 640000
#define EH_N 320000
#define NL 3

static inline int cdiv(int a, int b){ return (a+b-1)/b; }

typedef __attribute__((ext_vector_type(8))) short short8;
typedef __attribute__((ext_vector_type(4))) float f32x4;

// ---------------- compiled-in device scratch (no d_ws dependency) ----------------
__device__ float   g_h [(size_t)NN*DD];
__device__ unsigned short g_hb[(size_t)NN*DD];        // bf16 copy of h (GEMM A input)
__device__ unsigned short g_Wb[(size_t)NL*8*DD*DD];   // bf16, TRANSPOSED [n][k]; l*8 + {tQ,tK,tV,tS,hQ,hK,hV,hS}
__device__ float   g_Q [2][(size_t)NN*DD];
__device__ float   g_S [2][(size_t)NN*DD];
__device__ ushort2 g_KV[2][(size_t)NN*DD];   // .x = K bf16 bits, .y = V bf16 bits
__device__ float   g_to[(size_t)NN*DD];      // temporal conv output
__device__ float   g_ho[(size_t)NN*DD];      // host conv output
__device__ int     g_cnt[2][NN];
__device__ int     g_cur[2][NN];
__device__ int     g_rs [2][NN+1];
__device__ int     g_srcc[2][ET_N];          // CSR-ordered src (conv1 uses first EH_N)
__device__ float   g_ta[ET_N];               // CSR-ordered temporal attr (scalar)
__device__ float4  g_ha[EH_N];               // CSR-ordered host attr (3 used)
__device__ float   g_cf[NL][2][4][DD];       // folded edge-encoder coefs [l][conv][A0,A1,A2,B][ch]
__device__ float4  g_qe[2][(size_t)NN*4];    // per-(node,head): (qe0,qe1,qe2,qeB)

__device__ inline unsigned short f2bf(float f){
  unsigned u = __float_as_uint(f);
  unsigned r = (u + 0x7fffu + ((u>>16)&1u)) >> 16;   // RNE
  return (unsigned short)r;
}
__device__ inline float bf2f(unsigned short s){
  return __uint_as_float(((unsigned)s)<<16);
}
__device__ inline float bf_lo(unsigned u){ return __uint_as_float(u<<16); }
__device__ inline float bf_hi(unsigned u){ return __uint_as_float(u & 0xffff0000u); }

// ---------------- tiny helpers ----------------
__global__ void k_copy_h(const float* __restrict__ x){
  int i = blockIdx.x*256 + threadIdx.x;           // float4 index
  if (i < NN*DD/4){
    float4 v = reinterpret_cast<const float4*>(x)[i];
    reinterpret_cast<float4*>(g_h)[i] = v;
    ushort4 b; b.x=f2bf(v.x); b.y=f2bf(v.y); b.z=f2bf(v.z); b.w=f2bf(v.w);
    reinterpret_cast<ushort4*>(g_hb)[i] = b;
  }
}

__global__ void k_zero_cnt(){
  int i = blockIdx.x*256 + threadIdx.x;
  if (i < NN) g_cnt[blockIdx.y][i] = 0;
}

// convert + transpose conv weights to bf16 [n][k]
struct WPtrs { const float* W[24]; };
__global__ __launch_bounds__(256) void k_cvtw(WPtrs wp){
  int mat = blockIdx.y;
  const float* W = wp.W[mat];
  int e = blockIdx.x*256 + threadIdx.x;
  int n = e >> 7, k = e & 127;
  g_Wb[(size_t)mat*DD*DD + e] = f2bf(W[k*DD+n]);
}

// fold edge-encoder @ lin_edge for ALL layers: g_cf[l][conv][j][ch]
__global__ void k_coef(const float* __restrict__ WeT, const float* __restrict__ WeH,
                       const float* __restrict__ Wt,  const float* __restrict__ bt4,
                       const float* __restrict__ Wh,  const float* __restrict__ bh4){
  int ch = threadIdx.x;       // 128
  int conv = blockIdx.x;      // 2
  int l = blockIdx.y;         // NL
  float a0=0.f,a1=0.f,a2=0.f,b=0.f;
  if (conv==0){
    const float* We = WeT + (size_t)l*4*DD;
#pragma unroll
    for (int j=0;j<4;++j){ float w=We[j*DD+ch]; a0 += Wt[j]*w; b += bt4[j]*w; }
  } else {
    const float* We = WeH + (size_t)l*4*DD;
#pragma unroll
    for (int j=0;j<4;++j){
      float w=We[j*DD+ch];
      a0 += Wh[j]*w; a1 += Wh[4+j]*w; a2 += Wh[8+j]*w; b += bh4[j]*w;
    }
  }
  g_cf[l][conv][0][ch]=a0; g_cf[l][conv][1][ch]=a1;
  g_cf[l][conv][2][ch]=a2; g_cf[l][conv][3][ch]=b;
}

// per-(node,head) q.c scalars; one wave per node (2 ch/lane)
__global__ __launch_bounds__(256) void k_qe(int l){
  int conv = blockIdx.y;
  int wave = threadIdx.x>>6, lane = threadIdx.x&63;
  int i = blockIdx.x*4+wave; if (i>=NN) return;
  int d0 = lane*2;
  float2 q2 = *reinterpret_cast<const float2*>(&g_Q[conv][(size_t)i*DD+d0]);
  const float (*cf)[DD] = g_cf[l][conv];
  float s0 = q2.x*cf[0][d0] + q2.y*cf[0][d0+1];
  float s1 = q2.x*cf[1][d0] + q2.y*cf[1][d0+1];
  float s2 = q2.x*cf[2][d0] + q2.y*cf[2][d0+1];
  float s3 = q2.x*cf[3][d0] + q2.y*cf[3][d0+1];
#pragma unroll
  for (int mk=1; mk<=8; mk<<=1){
    s0 += __shfl_xor(s0,mk); s1 += __shfl_xor(s1,mk);
    s2 += __shfl_xor(s2,mk); s3 += __shfl_xor(s3,mk);
  }
  if ((lane&15)==0) g_qe[conv][(size_t)i*4 + (lane>>4)] = make_float4(s0,s1,s2,s3);
}

// ---------- CSR build (by destination) ----------
__global__ void k_hist(const int* __restrict__ dstT, const int* __restrict__ dstH){
  int which = blockIdx.y;
  int E = which ? EH_N : ET_N;
  const int* dst = which ? dstH : dstT;
  int e = blockIdx.x*256+threadIdx.x;
  if (e<E) atomicAdd(&g_cnt[which][dst[e]], 1);
}

__global__ __launch_bounds__(1024) void k_scan(){
  int which = blockIdx.y;
  int* row_start = g_rs[which];
  const int* cnt = g_cnt[which];
  int* cur = g_cur[which];
  __shared__ int buf[1024];
  int tid = threadIdx.x;
  const int n = NN;
  int chunk = (n + 1023) >> 10;
  int start = tid*chunk; if (start>n) start=n;
  int end = start+chunk; if (end>n) end=n;
  int lsum=0;
  for (int i=start;i<end;++i) lsum += cnt[i];
  buf[tid]=lsum;
  __syncthreads();
  for (int off=1; off<1024; off<<=1){
    int t = (tid>=off)? buf[tid-off]:0;
    __syncthreads();
    buf[tid] += t;
    __syncthreads();
  }
  int run = buf[tid]-lsum;
  for (int i=start;i<end;++i){ row_start[i]=run; cur[i]=run; run += cnt[i]; }
  if (tid==1023) row_start[n]=run;
}

// scatter: CSR-ordered src + raw edge attrs
__global__ void k_scatter(const int* __restrict__ eit, const int* __restrict__ eih,
                          const float* __restrict__ attrT, const float* __restrict__ attrH){
  int which = blockIdx.y;
  int e = blockIdx.x*256+threadIdx.x;
  if (which==0){
    if (e>=ET_N) return;
    int src = eit[e], dst = eit[ET_N+e];
    int p = atomicAdd(&g_cur[0][dst],1);
    g_srcc[0][p]=src;
    g_ta[p]=attrT[e];
  } else {
    if (e>=EH_N) return;
    int src = eih[e], dst = eih[EH_N+e];
    int p = atomicAdd(&g_cur[1][dst],1);
    g_srcc[1][p]=src;
    g_ha[p]=make_float4(attrH[e*3+0],attrH[e*3+1],attrH[e*3+2],0.f);
  }
}

// ---------- bf16 MFMA GEMM: one block computes Q,K,V,S for its 64-row tile ----------
// grid (cdiv(NN,64), 2): y = conv. A staged once; 4 B-phases, SINGLE-buffered
// (r9-proven; r10's double-buffer variant failed the repeat-call tripwire).
struct BiasP { const float* b[8]; };

__global__ __launch_bounds__(256) void k_gemm_mfma(int l, BiasP bp){
  __shared__ unsigned short lA[64*DD];    // 16 KB
  __shared__ unsigned short lB[DD*DD];    // 32 KB
  int conv = blockIdx.y;
  int setbase = l*8 + conv*4;             // +0 Q, +1 K, +2 V, +3 S
  int tid = threadIdx.x;
  int m0 = blockIdx.x*64;

  // stage A once
#pragma unroll
  for (int p=0;p<4;++p){
    int c = tid + p*256;
    int row = c >> 4, col16 = c & 15;
    int grow = m0 + row;
    uint4 v = make_uint4(0,0,0,0);
    if (grow < NN) v = *reinterpret_cast<const uint4*>(&g_hb[(size_t)grow*DD + col16*8]);
    int off = (row*256 + col16*16) ^ ((row&7)<<4);
    *reinterpret_cast<uint4*>((char*)lA + off) = v;
  }

  int wave = tid >> 6, lane = tid & 63;
  int lrow = lane & 15, kg = lane >> 4;
  int n0w = wave*32;

  auto stageB = [&](const unsigned short* Wm){
#pragma unroll
    for (int p=0;p<8;++p){
      int c = tid + p*256;
      int row = c >> 4, col16 = c & 15;
      uint4 v = *reinterpret_cast<const uint4*>(&Wm[(size_t)row*DD + col16*8]);
      int off = (row*256 + col16*16) ^ ((row&7)<<4);
      *reinterpret_cast<uint4*>((char*)lB + off) = v;
    }
  };

  stageB(&g_Wb[(size_t)(setbase+0)*DD*DD]);   // Q weights
  __syncthreads();

  // A fragments into registers (lA never overwritten)
  short8 a[4][4];
#pragma unroll
  for (int kk=0;kk<4;++kk){
    int kbyte = kk*64 + kg*16;
#pragma unroll
    for (int mi=0;mi<4;++mi){
      int row = mi*16 + lrow;
      int off = (row*256 + kbyte) ^ ((row&7)<<4);
      a[kk][mi] = *reinterpret_cast<const short8*>((char*)lA + off);
    }
  }

  auto computeC = [&](f32x4 (&acc)[4][2]){
#pragma unroll
    for (int mi=0;mi<4;++mi)
#pragma unroll
      for (int ni=0;ni<2;++ni) acc[mi][ni] = (f32x4){0.f,0.f,0.f,0.f};
#pragma unroll
    for (int kk=0;kk<4;++kk){
      int kbyte = kk*64 + kg*16;
      short8 b[2];
#pragma unroll
      for (int ni=0;ni<2;++ni){
        int n = n0w + ni*16 + lrow;
        int off = (n*256 + kbyte) ^ ((n&7)<<4);
        b[ni] = *reinterpret_cast<const short8*>((char*)lB + off);
      }
#pragma unroll
      for (int mi=0;mi<4;++mi)
#pragma unroll
        for (int ni=0;ni<2;++ni)
          acc[mi][ni] = __builtin_amdgcn_mfma_f32_16x16x32_bf16(a[kk][mi], b[ni], acc[mi][ni], 0,0,0);
    }
  };

  f32x4 acc[4][2], accK[4][2];

  // ---- Q ----
  computeC(acc);
  {
    const float* bias = bp.b[conv*4+0];
    float* op = g_Q[conv];
#pragma unroll
    for (int ni=0;ni<2;++ni){
      int col = n0w + ni*16 + lrow;
      float bs = bias[col];
#pragma unroll
      for (int mi=0;mi<4;++mi)
#pragma unroll
        for (int r=0;r<4;++r){
          int row = m0 + mi*16 + kg*4 + r;
          if (row < NN) op[(size_t)row*DD + col] = acc[mi][ni][r] + bs;
        }
    }
  }
  __syncthreads();
  // ---- K (keep in regs) ----
  stageB(&g_Wb[(size_t)(setbase+1)*DD*DD]);
  __syncthreads();
  computeC(accK);
  __syncthreads();
  // ---- V, then pack KV ----
  stageB(&g_Wb[(size_t)(setbase+2)*DD*DD]);
  __syncthreads();
  computeC(acc);
  {
    const float* bK = bp.b[conv*4+1];
    const float* bV = bp.b[conv*4+2];
#pragma unroll
    for (int ni=0;ni<2;++ni){
      int col = n0w + ni*16 + lrow;
      float bk = bK[col], bv = bV[col];
#pragma unroll
      for (int mi=0;mi<4;++mi)
#pragma unroll
        for (int r=0;r<4;++r){
          int row = m0 + mi*16 + kg*4 + r;
          if (row < NN){
            ushort2 kv;
            kv.x = f2bf(accK[mi][ni][r] + bk);
            kv.y = f2bf(acc [mi][ni][r] + bv);
            g_KV[conv][(size_t)row*DD + col] = kv;
          }
        }
    }
  }
  __syncthreads();
  // ---- S ----
  stageB(&g_Wb[(size_t)(setbase+3)*DD*DD]);
  __syncthreads();
  computeC(acc);
  {
    const float* bias = bp.b[conv*4+3];
    float* op = g_S[conv];
#pragma unroll
    for (int ni=0;ni<2;++ni){
      int col = n0w + ni*16 + lrow;
      float bs = bias[col];
#pragma unroll
      for (int mi=0;mi<4;++mi)
#pragma unroll
        for (int r=0;r<4;++r){
          int row = m0 + mi*16 + kg*4 + r;
          if (row < NN) op[(size_t)row*DD + col] = acc[mi][ni][r] + bs;
        }
    }
  }
}

// ---------- wave helpers ----------
__device__ inline float waveRed(float v){
  v += __shfl_xor(v,32); v += __shfl_xor(v,16); v += __shfl_xor(v,8);
  v += __shfl_xor(v,4);  v += __shfl_xor(v,2);  v += __shfl_xor(v,1);
  return v;
}

// ---------- per-dst-node attention aggregation ----------
// grid (cdiv(NN,4), 2); block 256 = 4 independent waves, one node per wave.
// subgroup g = lane>>4 handles edges beg+it*4+g; sublane t = lane&15 holds
// channels 8t..8t+7 (head = t>>2). qe + coefficients precomputed (k_qe/k_coef).
__global__ __launch_bounds__(256) void k_agg(int l){
  int conv = blockIdx.y;
  int wave = threadIdx.x >> 6;
  int lane = threadIdx.x & 63;
  int i = blockIdx.x*4 + wave;
  if (i >= NN) return;
  int g = lane >> 4;
  int t = lane & 15;
  int ch0 = t*8;

  const float* Qi = &g_Q[conv][(size_t)i*DD + ch0];
  float q[8];
  {
    float4 qA = *reinterpret_cast<const float4*>(Qi);
    float4 qB = *reinterpret_cast<const float4*>(Qi+4);
    q[0]=qA.x;q[1]=qA.y;q[2]=qA.z;q[3]=qA.w;q[4]=qB.x;q[5]=qB.y;q[6]=qB.z;q[7]=qB.w;
  }
  float4 qe = g_qe[conv][(size_t)i*4 + (t>>2)];   // (qe0,qe1,qe2,qeB)

  const int* srcc = g_srcc[conv];
  const char* KVbase = (const char*)g_KV[conv];
  int beg=g_rs[conv][i], end=g_rs[conv][i+1];
  int cnt = end-beg;

  const float inv32 = 0.17677669529663687f;   // 1/sqrt(32)
  float den=0.f, x0=0.f, x1=0.f, x2=0.f;
  float ac[8];
#pragma unroll
  for (int r=0;r<8;++r) ac[r]=0.f;

  if (cnt>0){
    int nit = (cnt+3)>>2;
    int idx = beg + g;
    bool val = idx < end;
    int sidx = val ? idx : beg;
    int s = srcc[sidx];
    float4 at = make_float4(0.f,0.f,0.f,0.f);
    if (conv==0) at.x = g_ta[sidx]; else at = g_ha[sidx];
    const uint4* rp = reinterpret_cast<const uint4*>(KVbase + (size_t)s*512 + t*32);
    uint4 u0 = rp[0], u1 = rp[1];

    for (int it=0; it<nit; ++it){
      uint4 cu0=u0, cu1=u1; float4 ca=at; bool cval=val;
      if (it+1<nit){
        int nidx = beg + (it+1)*4 + g;
        val = nidx < end;
        int ns = srcc[val?nidx:beg];
        if (conv==0) at.x = g_ta[val?nidx:beg]; else at = g_ha[val?nidx:beg];
        rp = reinterpret_cast<const uint4*>(KVbase + (size_t)ns*512 + t*32);
        u0 = rp[0]; u1 = rp[1];
      }
      float k[8], v[8];
      k[0]=bf_lo(cu0.x); v[0]=bf_hi(cu0.x);
      k[1]=bf_lo(cu0.y); v[1]=bf_hi(cu0.y);
      k[2]=bf_lo(cu0.z); v[2]=bf_hi(cu0.z);
      k[3]=bf_lo(cu0.w); v[3]=bf_hi(cu0.w);
      k[4]=bf_lo(cu1.x); v[4]=bf_hi(cu1.x);
      k[5]=bf_lo(cu1.y); v[5]=bf_hi(cu1.y);
      k[6]=bf_lo(cu1.z); v[6]=bf_hi(cu1.z);
      k[7]=bf_lo(cu1.w); v[7]=bf_hi(cu1.w);
      float p = 0.f;
#pragma unroll
      for (int r=0;r<8;++r) p += q[r]*k[r];
      p += __shfl_xor(p,1); p += __shfl_xor(p,2);   // head dot (32 ch)
      float lg = (conv==0) ? (p + qe.w + ca.x*qe.x)*inv32
                           : (p + ca.x*qe.x + ca.y*qe.y + ca.z*qe.z + qe.w)*inv32;
      float e = cval ? __expf(lg) : 0.f;
      den += e;
#pragma unroll
      for (int r=0;r<8;++r) ac[r] += e*v[r];
      x0 += e*ca.x;
      if (conv==1){ x1 += e*ca.y; x2 += e*ca.z; }
    }
    den += __shfl_xor(den,16); den += __shfl_xor(den,32);
    x0  += __shfl_xor(x0,16);  x0  += __shfl_xor(x0,32);
    if (conv==1){
      x1 += __shfl_xor(x1,16); x1 += __shfl_xor(x1,32);
      x2 += __shfl_xor(x2,16); x2 += __shfl_xor(x2,32);
    }
#pragma unroll
    for (int r=0;r<8;++r){ ac[r] += __shfl_xor(ac[r],16); ac[r] += __shfl_xor(ac[r],32); }
  }

  if (g==0){
    const float (*cf)[DD] = g_cf[l][conv];
    float cA0[8], cA1[8], cA2[8], cB[8];
    {
      float4 a0A=*reinterpret_cast<const float4*>(&cf[0][ch0]);
      float4 a0B=*reinterpret_cast<const float4*>(&cf[0][ch0+4]);
      float4 a1A=*reinterpret_cast<const float4*>(&cf[1][ch0]);
      float4 a1B=*reinterpret_cast<const float4*>(&cf[1][ch0+4]);
      float4 a2A=*reinterpret_cast<const float4*>(&cf[2][ch0]);
      float4 a2B=*reinterpret_cast<const float4*>(&cf[2][ch0+4]);
      float4 bA =*reinterpret_cast<const float4*>(&cf[3][ch0]);
      float4 bB =*reinterpret_cast<const float4*>(&cf[3][ch0+4]);
      cA0[0]=a0A.x;cA0[1]=a0A.y;cA0[2]=a0A.z;cA0[3]=a0A.w;cA0[4]=a0B.x;cA0[5]=a0B.y;cA0[6]=a0B.z;cA0[7]=a0B.w;
      cA1[0]=a1A.x;cA1[1]=a1A.y;cA1[2]=a1A.z;cA1[3]=a1A.w;cA1[4]=a1B.x;cA1[5]=a1B.y;cA1[6]=a1B.z;cA1[7]=a1B.w;
      cA2[0]=a2A.x;cA2[1]=a2A.y;cA2[2]=a2A.z;cA2[3]=a2A.w;cA2[4]=a2B.x;cA2[5]=a2B.y;cA2[6]=a2B.z;cA2[7]=a2B.w;
      cB[0]=bA.x;cB[1]=bA.y;cB[2]=bA.z;cB[3]=bA.w;cB[4]=bB.x;cB[5]=bB.y;cB[6]=bB.z;cB[7]=bB.w;
    }
    float r8[8];
    if (cnt==0){
#pragma unroll
      for (int r=0;r<8;++r) r8[r]=0.f;
    } else {
      float id = 1.f/den;
      if (conv==0){
        float xm = x0*id;
#pragma unroll
        for (int r=0;r<8;++r) r8[r] = ac[r]*id + cB[r] + cA0[r]*xm;
      } else {
        float xm0=x0*id, xm1=x1*id, xm2=x2*id;
#pragma unroll
        for (int r=0;r<8;++r) r8[r] = ac[r]*id + cA0[r]*xm0 + cA1[r]*xm1 + cA2[r]*xm2 + cB[r];
      }
    }
    const float* Si = &g_S[conv][(size_t)i*DD + ch0];
    float4 sA = *reinterpret_cast<const float4*>(Si);
    float4 sB = *reinterpret_cast<const float4*>(Si+4);
    float* o = (conv ? g_ho : g_to) + (size_t)i*DD + ch0;
    float4 oA, oB;
    oA.x=r8[0]+sA.x; oA.y=r8[1]+sA.y; oA.z=r8[2]+sA.z; oA.w=r8[3]+sA.w;
    oB.x=r8[4]+sB.x; oB.y=r8[5]+sB.y; oB.z=r8[6]+sB.z; oB.w=r8[7]+sB.w;
    *reinterpret_cast<float4*>(o)   = oA;
    *reinterpret_cast<float4*>(o+4) = oB;
  }
}

// g_h += silu(layernorm(g_to + g_ho)) ; one wave per node, 4 nodes per block
__global__ __launch_bounds__(256) void k_combine(const float* __restrict__ g, const float* __restrict__ bt){
  int lane = threadIdx.x & 63;
  int node = blockIdx.x*4 + (threadIdx.x>>6);
  if (node>=NN) return;
  size_t i0 = (size_t)node*DD + lane, i1 = i0+64;
  float v0 = g_to[i0] + g_ho[i0];
  float v1 = g_to[i1] + g_ho[i1];
  float s = waveRed(v0+v1);
  float mean = s*(1.f/128.f);
  float d0=v0-mean, d1=v1-mean;
  float q = waveRed(d0*d0+d1*d1);
  float inv = 1.f/sqrtf(q*(1.f/128.f)+1e-5f);
  float c0 = d0*inv*g[lane]+bt[lane];
  float c1 = d1*inv*g[lane+64]+bt[lane+64];
  float h0 = g_h[i0] + c0/(1.f+__expf(-c0));
  float h1 = g_h[i1] + c1/(1.f+__expf(-c1));
  g_h[i0] = h0; g_h[i1] = h1;
  g_hb[i0] = f2bf(h0); g_hb[i1] = f2bf(h1);
}

// in-place final layernorm on g_h
__global__ __launch_bounds__(256) void k_finalln(const float* __restrict__ g, const float* __restrict__ b){
  int lane = threadIdx.x & 63;
  int node = blockIdx.x*4 + (threadIdx.x>>6);
  if (node>=NN) return;
  size_t i0 = (size_t)node*DD + lane, i1 = i0+64;
  float v0 = g_h[i0], v1 = g_h[i1];
  float s = waveRed(v0+v1);
  float mean = s*(1.f/128.f);
  float d0=v0-mean, d1=v1-mean;
  float q = waveRed(d0*d0+d1*d1);
  float inv = 1.f/sqrtf(q*(1.f/128.f)+1e-5f);
  g_h[i0]=d0*inv*g[lane]+b[lane];
  g_h[i1]=d1*inv*g[lane+64]+b[lane+64];
}

// mlp head: out3 = LN(silu(g_h@W1+b1)) @ W2 + b2 ; 8 nodes per block; y = which head
struct HeadP { const float* W1; const float* b1; const float* g; const float* bt;
               const float* W2; const float* b2; float* out; };
__global__ __launch_bounds__(128) void k_head(HeadP h0, HeadP h1){
  const HeadP hp = blockIdx.y ? h1 : h0;
  const float* __restrict__ W1 = hp.W1;
  const float* __restrict__ b1 = hp.b1;
  const float* __restrict__ g  = hp.g;
  const float* __restrict__ bt = hp.bt;
  const float* __restrict__ W2 = hp.W2;
  const float* __restrict__ b2 = hp.b2;
  float* __restrict__ out = hp.out;
  int d = threadIdx.x;
  int wv = d >> 6;
  int i0 = blockIdx.x*8;
  const int n = NN;
  __shared__ float rows[8][DD];
  __shared__ float comb[2];
#pragma unroll
  for (int t=0;t<8;++t){
    int node = i0+t;
    rows[t][d] = (node<n)? g_h[(size_t)node*DD+d] : 0.f;
  }
  __syncthreads();
  float z[8];
  float b1d = b1[d];
#pragma unroll
  for (int t=0;t<8;++t) z[t]=b1d;
  for (int k=0;k<DD;++k){
    float w = W1[k*DD+d];
#pragma unroll
    for (int t=0;t<8;++t) z[t] += rows[t][k]*w;
  }
#pragma unroll
  for (int t=0;t<8;++t){ float v=z[t]; z[t] = v/(1.f+expf(-v)); }
  float gd=g[d], btd=bt[d];
  float w2a=W2[d*3+0], w2b=W2[d*3+1], w2c=W2[d*3+2];
  float b2a=b2[0], b2b=b2[1], b2c=b2[2];
  for (int t=0;t<8;++t){
    int node=i0+t;
    float zz=z[t];
    float s = waveRed(zz);
    if ((d&63)==0) comb[wv]=s;
    __syncthreads();
    float mean=(comb[0]+comb[1])*(1.f/128.f);
    __syncthreads();
    float dv=zz-mean;
    float q2 = waveRed(dv*dv);
    if ((d&63)==0) comb[wv]=q2;
    __syncthreads();
    float inv = 1.f/sqrtf((comb[0]+comb[1])*(1.f/128.f)+1e-5f);
    __syncthreads();
    float zn = dv*inv*gd+btd;
    float p0 = waveRed(zn*w2a);
    if ((d&63)==0) comb[wv]=p0;
    __syncthreads();
    float o0 = comb[0]+comb[1]+b2a;
    __syncthreads();
    float p1 = waveRed(zn*w2b);
    if ((d&63)==0) comb[wv]=p1;
    __syncthreads();
    float o1 = comb[0]+comb[1]+b2b;
    __syncthreads();
    float p2 = waveRed(zn*w2c);
    if ((d&63)==0) comb[wv]=p2;
    __syncthreads();
    float o2 = comb[0]+comb[1]+b2c;
    __syncthreads();
    if (d==0 && node<n){
      out[(size_t)node*3+0]=o0; out[(size_t)node*3+1]=o1; out[(size_t)node*3+2]=o2;
    }
  }
}

extern "C" void kernel_launch(void* const* d_in, const int* in_sizes, int n_in,
                              void* d_out, int out_size, void* d_ws, size_t ws_size,
                              hipStream_t stream){
  (void)in_sizes; (void)n_in; (void)out_size; (void)d_ws; (void)ws_size;
  const float* x    = (const float*)d_in[0];
  const int*   eit  = (const int*)d_in[1];
  const int*   eih  = (const int*)d_in[2];
  const float* eat  = (const float*)d_in[3];
  const float* eah  = (const float*)d_in[4];
  const float* W_te = (const float*)d_in[5];
  const float* b_te = (const float*)d_in[6];
  const float* W_he = (const float*)d_in[7];
  const float* b_he = (const float*)d_in[8];
  const float *Wq_t=(const float*)d_in[9],  *bq_t=(const float*)d_in[10];
  const float *Wk_t=(const float*)d_in[11], *bk_t=(const float*)d_in[12];
  const float *Wv_t=(const float*)d_in[13], *bv_t=(const float*)d_in[14];
  const float *We_t=(const float*)d_in[15];
  const float *Ws_t=(const float*)d_in[16], *bs_t=(const float*)d_in[17];
  const float *Wq_h=(const float*)d_in[18], *bq_h=(const float*)d_in[19];
  const float *Wk_h=(const float*)d_in[20], *bk_h=(const float*)d_in[21];
  const float *Wv_h=(const float*)d_in[22], *bv_h=(const float*)d_in[23];
  const float *We_h=(const float*)d_in[24];
  const float *Ws_h=(const float*)d_in[25], *bs_h=(const float*)d_in[26];
  const float *norm_g=(const float*)d_in[27], *norm_b=(const float*)d_in[28];
  const float *fg=(const float*)d_in[29], *fb=(const float*)d_in[30];
  const float *dW1=(const float*)d_in[31], *db1=(const float*)d_in[32];
  const float *dg=(const float*)d_in[33],  *dbt=(const float*)d_in[34];
  const float *dW2=(const float*)d_in[35], *db2=(const float*)d_in[36];
  const float *sW1=(const float*)d_in[37], *sb1=(const float*)d_in[38];
  const float *sg=(const float*)d_in[39],  *sbt=(const float*)d_in[40];
  const float *sW2=(const float*)d_in[41], *sb2=(const float*)d_in[42];
  float* outp = (float*)d_out;

  k_copy_h<<<cdiv(NN*DD/4,256),256,0,stream>>>(x);

  WPtrs wp;
  for (int l=0;l<NL;++l){
    wp.W[l*8+0]=Wq_t+(size_t)l*DD*DD; wp.W[l*8+1]=Wk_t+(size_t)l*DD*DD;
    wp.W[l*8+2]=Wv_t+(size_t)l*DD*DD; wp.W[l*8+3]=Ws_t+(size_t)l*DD*DD;
    wp.W[l*8+4]=Wq_h+(size_t)l*DD*DD; wp.W[l*8+5]=Wk_h+(size_t)l*DD*DD;
    wp.W[l*8+6]=Wv_h+(size_t)l*DD*DD; wp.W[l*8+7]=Ws_h+(size_t)l*DD*DD;
  }
  k_cvtw<<<dim3(64,24),256,0,stream>>>(wp);
  k_coef<<<dim3(2,NL),128,0,stream>>>(We_t, We_h, W_te, b_te, W_he, b_he);

  k_zero_cnt<<<dim3(cdiv(NN,256),2),256,0,stream>>>();
  k_hist<<<dim3(cdiv(ET_N,256),2),256,0,stream>>>(eit+ET_N, eih+EH_N);
  k_scan<<<dim3(1,2),1024,0,stream>>>();
  k_scatter<<<dim3(cdiv(ET_N,256),2),256,0,stream>>>(eit, eih, eat, eah);

  for (int l=0;l<NL;++l){
    BiasP bp;
    bp.b[0]=bq_t+(size_t)l*DD; bp.b[1]=bk_t+(size_t)l*DD;
    bp.b[2]=bv_t+(size_t)l*DD; bp.b[3]=bs_t+(size_t)l*DD;
    bp.b[4]=bq_h+(size_t)l*DD; bp.b[5]=bk_h+(size_t)l*DD;
    bp.b[6]=bv_h+(size_t)l*DD; bp.b[7]=bs_h+(size_t)l*DD;
    k_gemm_mfma<<<dim3(cdiv(NN,64),2),256,0,stream>>>(l, bp);
    k_qe<<<dim3(cdiv(NN,4),2),256,0,stream>>>(l);
    k_agg<<<dim3(cdiv(NN,4),2),256,0,stream>>>(l);
    k_combine<<<cdiv(NN,4),256,0,stream>>>(norm_g+(size_t)l*DD, norm_b+(size_t)l*DD);
  }
  k_finalln<<<cdiv(NN,4),256,0,stream>>>(fg, fb);
  HeadP hd, hs;
  hd.W1=dW1; hd.b1=db1; hd.g=dg; hd.bt=dbt; hd.W2=dW2; hd.b2=db2; hd.out=outp;
  hs.W1=sW1; hs.b1=sb1; hs.g=sg; hs.bt=sbt; hs.W2=sW2; hs.b2=sb2; hs.out=outp+(size_t)NN*3;
  k_head<<<dim3(cdiv(NN,8),2),128,0,stream>>>(hd, hs);
}